// Round 11
// baseline (77.721 us; speedup 1.0000x reference)
//
#include <hip/hip_runtime.h>

#define B_TOTAL 262144
#define K_CB    512
#define D_DIM   3
#define BLOCK   256
#define NSLOT   (B_TOTAL * D_DIM)      // 786432 flat scalar slots
#define LUT_S   1032                   // per-dim u16 stride (u32-aligned)

// monotone map fp32 bits -> uint32 (ascending float => ascending uint)
__device__ __forceinline__ unsigned int mono32(unsigned int u) {
    unsigned int m = (u & 0x80000000u) ? 0xFFFFFFFFu : 0x80000000u;
    return u ^ m;
}

// bucket id: monotone in x (fp32 add, exact *2^7, floor, clamp); the SAME
// expression is used on codebook values (K1) and queries (K2).
__device__ __forceinline__ int bucket_of(float x) {
    float tf = floorf((x + 4.0f) * 128.0f);
    tf = fminf(fmaxf(tf, 0.0f), 1023.0f);
    return (int)tf;
}

// ---------------- kernel 1: rank-sort codebook + bucket-prefix LUT -----------
// 6 blocks = (d, half). ws: ws_val f32[3*512] | ws_idx i32[3*512] |
// ws_lut u16[3*1032]  with  L[i] = #{k : bucket(e_k) < i}, i in [0,1024].
__global__ __launch_bounds__(BLOCK) void rank_lut_kernel(
    const float* __restrict__ e, float* __restrict__ ws_val,
    int* __restrict__ ws_idx, unsigned short* __restrict__ ws_lut)
{
    const int d    = blockIdx.x >> 1;
    const int half = blockIdx.x & 1;
    const int tid  = threadIdx.x;

    __shared__ unsigned long long key[K_CB];   // 4 KB
    __shared__ float              val[K_CB];   // 2 KB
    __shared__ int                bkt[K_CB];   // 2 KB

    for (int k = tid; k < K_CB; k += BLOCK) {
        float v = e[k * D_DIM + d];
        key[k] = ((unsigned long long)mono32(__float_as_uint(v)) << 32)
               | (unsigned int)k;
        val[k] = v;
        bkt[k] = bucket_of(v);
    }
    __syncthreads();

    // stable rank (value, orig idx) — R8-validated
    const int i = half * BLOCK + tid;
    const unsigned long long mykey = key[i];
    int rank = 0;
    #pragma unroll 8
    for (int j = 0; j < K_CB; ++j)             // wave-uniform LDS: broadcast
        rank += (key[j] < mykey) ? 1 : 0;

    ws_val[d * K_CB + rank] = val[i];
    ws_idx[d * K_CB + rank] = i;

    // LUT: this block covers targets [half*512, half*512+512)
    const int i0 = half * 512 + tid;
    const int i1 = i0 + BLOCK;
    int c0 = 0, c1 = 0;
    #pragma unroll 8
    for (int j = 0; j < K_CB; ++j) {
        int bj = bkt[j];                       // wave-uniform LDS: broadcast
        c0 += (bj < i0) ? 1 : 0;
        c1 += (bj < i1) ? 1 : 0;
    }
    ws_lut[d * LUT_S + i0] = (unsigned short)c0;
    ws_lut[d * LUT_S + i1] = (unsigned short)c1;
    if (half == 1 && tid == 0)
        ws_lut[d * LUT_S + 1024] = (unsigned short)K_CB;  // L[1024] == 512
}

// ---------------- kernel 2: LUT-bracketed fixed-step search ------------------
__global__ __launch_bounds__(BLOCK) void vq_search_kernel(
    const float* __restrict__ ze,
    const float* __restrict__ ws_val, const int* __restrict__ ws_idx,
    const unsigned int* __restrict__ ws_lut_u32,
    float* __restrict__ z_out, float* __restrict__ zq_out)
{
    __shared__ __align__(16) float          sval[D_DIM * K_CB];  // 6 KB
    __shared__ __align__(16) int            sidx[D_DIM * K_CB];  // 6 KB
    __shared__ __align__(4)  unsigned short slut[D_DIM * LUT_S]; // 6.05 KB

    const int tid = threadIdx.x;
    {   // vectorized staging
        const float4* gv = (const float4*)ws_val; float4* lv = (float4*)sval;
        for (int i = tid; i < D_DIM * K_CB / 4; i += BLOCK) lv[i] = gv[i];
        const int4*   gi = (const int4*)ws_idx;   int4*   li = (int4*)sidx;
        for (int i = tid; i < D_DIM * K_CB / 4; i += BLOCK) li[i] = gi[i];
        unsigned int* ll = (unsigned int*)slut;
        for (int i = tid; i < D_DIM * LUT_S / 2; i += BLOCK) ll[i] = ws_lut_u32[i];
    }
    __syncthreads();

    const int s4 = (blockIdx.x * BLOCK + tid) * 4;    // 4 consecutive flat slots
    const float4 xv4 = *(const float4*)(ze + s4);
    const float xs[4] = { xv4.x, xv4.y, xv4.z, xv4.w };

    int dcur = s4 % 3;
    float zz[4], zq[4];

    #pragma unroll
    for (int q = 0; q < 4; ++q) {
        const int base = dcur * K_CB;
        const int lutb = dcur * LUT_S;
        dcur = (dcur == 2) ? 0 : dcur + 1;
        const float xv = xs[q];

        // bracket from LUT: lo in [L[t]-1, L[t+1]-1], sval[L[t+1]] > xv strictly
        const int t  = bucket_of(xv);
        int lo = (int)slut[lutb + t] - 1;
        int hi = (int)slut[lutb + t + 1];

        if (hi - lo > 16) {           // provable fallback (never for this data)
            lo = -1; hi = K_CB;
            #pragma unroll
            for (int it = 0; it < 10; ++it) {
                int mid = (lo + hi) >> 1;
                bool le = sval[base + mid] <= xv;
                lo = le ? mid : lo;
                hi = le ? hi : mid;
            }
        } else {
            // fixed 4 steps resolve window <= 16; invariant
            // sval[lo] <= xv < sval[hi] (virtual sentinels -1 / 512)
            #pragma unroll
            for (int it = 0; it < 4; ++it) {
                int mid = (lo + hi) >> 1;
                bool le = sval[base + mid] <= xv;
                lo = le ? mid : lo;
                hi = le ? hi : mid;
            }
        }

        // left candidate: walk back to head of equal-value run (min orig idx)
        float dl = 3.402823466e38f, vl = 0.0f; int il = 0;
        if (lo >= 0) {
            vl = sval[base + lo];
            int p = lo;
            while (p > 0 && sval[base + p - 1] == vl) --p;
            il = sidx[base + p];
            float tt = xv - vl;                // identical fp32 arith to ref
            dl = tt * tt;
        }
        // right candidate: nearest value > xv (group head == lo+1)
        float dr = 3.402823466e38f, vr = 0.0f; int ir = 0;
        if (lo < K_CB - 1) {
            vr = sval[base + lo + 1];
            ir = sidx[base + lo + 1];
            float tt = xv - vr;
            dr = tt * tt;
        }

        // np.argmin semantics: strict min; tie -> smaller original index
        const bool pickR = (dr < dl) || ((dr == dl) && (ir < il));
        zz[q] = (float)(pickR ? ir : il);
        zq[q] = pickR ? vr : vl;
    }

    *(float4*)(z_out  + s4) = make_float4(zz[0], zz[1], zz[2], zz[3]);
    *(float4*)(zq_out + s4) = make_float4(zq[0], zq[1], zq[2], zq[3]);
}

extern "C" void kernel_launch(void* const* d_in, const int* in_sizes, int n_in,
                              void* d_out, int out_size, void* d_ws, size_t ws_size,
                              hipStream_t stream) {
    const float* ze = (const float*)d_in[0];
    const float* e  = (const float*)d_in[1];
    float* z_out  = (float*)d_out;                    // z  : B*D float32
    float* zq_out = z_out + (size_t)NSLOT;            // zq : B*D float32

    float*          ws_val = (float*)d_ws;                         // [3*512] f32
    int*            ws_idx = (int*)(ws_val + D_DIM * K_CB);        // [3*512] i32
    unsigned short* ws_lut = (unsigned short*)(ws_idx + D_DIM * K_CB); // [3*1032]

    rank_lut_kernel <<<D_DIM * 2,           BLOCK, 0, stream>>>(e, ws_val, ws_idx, ws_lut);
    vq_search_kernel<<<NSLOT / (4 * BLOCK), BLOCK, 0, stream>>>(
        ze, ws_val, ws_idx, (const unsigned int*)ws_lut, z_out, zq_out);
}